// Round 21
// baseline (28.110 us; speedup 1.0000x reference)
//
#include <hip/hip_runtime.h>
#include <hip/hip_bf16.h>
#include <math.h>

#define N 1024
#define TB 16

typedef __attribute__((ext_vector_type(8))) short short8;
typedef __attribute__((ext_vector_type(4))) short short4v;
typedef __attribute__((ext_vector_type(4))) float f32x4;

// PReLU for 0 <= a <= 1 (here a = 0.25): max(v, a*v) — bit-identical to
// max(v,0) + a*min(v,0). 2 VALU ops.
__device__ __forceinline__ float prelu(float v, float a) {
    return fmaxf(v, a * v);
}

// f32 -> bf16 RNE via hardware cvt (pairs into v_cvt_pk_bf16_f32)
__device__ __forceinline__ unsigned short f2bfu(float f) {
    return __bfloat16_as_ushort(__float2bfloat16(f));
}

// ---------- kernel 1: one-block weight prep (runs once per call) ----------
// ws[0..511]    = W2F  : lane l = khkw*16+oc holds W2[oc][k=g*8+j] at [l*8+j]
// ws[512..1023] = W3F0 : lane l = g*16+c16 holds W3 frag k=g*8+j (k<32); c16>=8 zero
// ws[1024..1535]= W3F1 : same for k>=32
__global__ void prep_weights(const float* __restrict__ w2,
                             const float* __restrict__ w3,
                             unsigned short* __restrict__ ws)
{
    const int tid = threadIdx.x;   // 256 threads
    // W2F: element s = o*32 + i*4 + khkw  ->  lane (khkw*16+o), slot i
    for (int s = tid; s < 512; s += 256) {
        int dst = ((s & 3) * 16 + (s >> 5)) * 8 + ((s >> 2) & 7);
        ws[dst] = f2bfu(w2[s]);
    }
    // zero W3F0/F1 fully (covers c16>=8 lanes), then scatter real values
    for (int q = tid; q < 1024; q += 256) ws[512 + q] = 0;
    __syncthreads();
    // W3: element s (oc=s>>6, i=(s>>2)&15, khkw=s&3):
    //   half = (s>>1)&1 ; g = ((s&1)<<1)|((s>>5)&1) ; j = (s>>2)&7
    for (int s = tid; s < 512; s += 256) {
        int half = (s >> 1) & 1;
        int gg = ((s & 1) << 1) | ((s >> 5) & 1);
        int dst = 512 + half * 512 + ((gg * 16 + (s >> 6)) * 8) + ((s >> 2) & 7);
        ws[dst] = f2bfu(w3[s]);
    }
}

// ---------- kernel 2: main (R20 skeleton, weight staging removed) ----------
__global__ __launch_bounds__(256, 8) void precond_mfma(
    const float* __restrict__ xg, const int* __restrict__ maskg,
    const float* __restrict__ w1, const float* __restrict__ b1, const float* __restrict__ a1p,
    const float* __restrict__ b2, const float* __restrict__ a2p,
    const float* __restrict__ b3, const float* __restrict__ a3p,
    const float* __restrict__ w4, const float* __restrict__ b4p,
    const unsigned short* __restrict__ wsW,
    float* __restrict__ out)
{
    const int tid = threadIdx.x;
    const int bz  = blockIdx.z;
    const int t   = blockIdx.x;

    // ---- triangular mapping: t -> (by, bx), bx <= by ----
    int by = (int)((sqrtf(8.0f * (float)t + 1.0f) - 1.0f) * 0.5f);
    while ((by + 1) * (by + 2) / 2 <= t) ++by;
    while (by * (by + 1) / 2 > t) --by;
    const int bx = t - by * (by + 1) / 2;
    const int ty0 = by * TB, tx0 = bx * TB;

    const int lane = tid & 63, wid = tid >> 6;
    const int c16 = lane & 15, g = lane >> 4;

    // ================= EARLY GLOBAL LOADS (issued up front) =================
    // W2 A-fragment: one coalesced 16B/lane load (prepared fragment-major)
    const short8 a2f = *(const short8*)&wsW[lane * 8];

    // parameter vectors, vectorized — consumed from registers only
    const float4 w1lo = *(const float4*)&w1[0];
    const float4 w1hi = *(const float4*)&w1[4];
    const float4 b1lo = *(const float4*)&b1[0];
    const float4 b1hi = *(const float4*)&b1[4];
    const float4 b2v  = *(const float4*)&b2[g * 4];
    const int gsel = (g < 2) ? g : 0;
    float4 b3v = *(const float4*)&b3[gsel * 4];
    float4 w4v = *(const float4*)&w4[gsel * 4];
    const float a1 = a1p[0], a2 = a2p[0], a3 = a3p[0];
    const float b4 = b4p[0];

    const float w1a[8] = {w1lo.x, w1lo.y, w1lo.z, w1lo.w, w1hi.x, w1hi.y, w1hi.z, w1hi.w};
    const float b1a[8] = {b1lo.x, b1lo.y, b1lo.z, b1lo.w, b1hi.x, b1hi.y, b1hi.z, b1hi.w};

    // Phase A positions (324 over 256 threads: 2 slots)
    const int pA0 = tid;
    const int pA1 = tid + 256;
    const bool s1valid = (pA1 < 324);
    const bool s1wave  = ((tid - lane) + 256 < 324);   // waves 0,1
    const int dyA0 = pA0 / 18, dxA0 = pA0 - dyA0 * 18;
    const int dyA1 = pA1 / 18, dxA1 = pA1 - dyA1 * 18;

    int gy0 = ty0 - 1 + dyA0, gx0 = tx0 - 1 + dxA0;
    const bool in0 = (unsigned)gy0 < N && (unsigned)gx0 < N;
    size_t i0 = in0 ? (((size_t)bz * N + gy0) * N + gx0) : 0;
    const int   mr0 = maskg[i0];
    const float xr0 = xg[i0];

    int mr1 = 0; float xr1 = 0.f; bool in1 = false;
    if (s1wave) {
        int gy1 = ty0 - 1 + dyA1, gx1 = tx0 - 1 + dxA1;
        in1 = s1valid && (unsigned)gy1 < N && (unsigned)gx1 < N;
        size_t i1 = in1 ? (((size_t)bz * N + gy1) * N + gx1) : 0;
        mr1 = maskg[i1];
        xr1 = xg[i1];
    }

    // zero b3/w4 fragments for g>=2 lanes (off critical path)
    if (g >= 2) {
        b3v = make_float4(0.f, 0.f, 0.f, 0.f);
        w4v = make_float4(0.f, 0.f, 0.f, 0.f);
    }

    // ---- fused zero-fill (closed form): upper tile = (row=bx, col=by+1) ----
    if (by < 63) {
        int zy = bx * TB + (tid >> 4), zx = (by + 1) * TB + (tid & 15);
        out[((size_t)bz * N + zy) * N + zx] = 0.f;   // fire-and-forget
    }

    __shared__ __align__(16) short h1s[324 * 8];    // [pos 18x18][8ch] bf16
    __shared__ __align__(16) short h2lo[4][85 * 8]; // per-wave: [pos 5x17][ch 0-7]
    __shared__ __align__(16) short h2hi[4][85 * 8]; // per-wave: [pos 5x17][ch 8-15]
    __shared__ __align__(16) unsigned RM1[12];      // 324-bit layer-1 mask bitmap

    const bool leftEdge  = (tx0 == 0);
    const bool rightEdge = (tx0 == N - TB);

    // ---- Phase A: h1 + ballot mask bitmap (consume early loads) ----
    {
        bool mb = in0 && (mr0 > 0);
        float xv = in0 ? xr0 : 0.f;
        unsigned long long bal = __ballot(mb);
        if (lane == 0) *(uint2*)&RM1[2 * wid] = make_uint2((unsigned)bal, (unsigned)(bal >> 32));
        short8 hv;
#pragma unroll
        for (int ch = 0; ch < 8; ++ch) hv[ch] = (short)f2bfu(prelu(fmaf(xv, w1a[ch], b1a[ch]), a1));
        if (!mb) hv = (short8)0;
        *(short8*)&h1s[pA0 * 8] = hv;

        if (s1wave) {
            bool mb1 = in1 && (mr1 > 0);
            float xv1 = in1 ? xr1 : 0.f;
            unsigned long long bal1 = __ballot(mb1);
            if (lane == 0) *(uint2*)&RM1[2 * (wid + 4)] = make_uint2((unsigned)bal1, (unsigned)(bal1 >> 32));
            if (s1valid) {
                short8 hv1;
#pragma unroll
                for (int ch = 0; ch < 8; ++ch) hv1[ch] = (short)f2bfu(prelu(fmaf(xv1, w1a[ch], b1a[ch]), a1));
                if (!mb1) hv1 = (short8)0;
                *(short8*)&h1s[pA1 * 8] = hv1;
            }
        }
    }
    __syncthreads();   // the ONLY barrier

    // W3 A-fragments: issued here so their L2 latency hides under mask-build
    // and Phase B; consumed only in Phase C. Coalesced 16B/lane, L2-hot.
    const short8 a3f0 = *(const short8*)&wsW[512 + lane * 8];
    const short8 a3f1 = *(const short8*)&wsW[1024 + lane * 8];

    // ---- per-wave spread masks in registers: m2row[5] (17 bits) + col16bits ----
    unsigned m2row[5];
    unsigned col16bits;
    {
        const int bitbase = 72 * wid;     // 18 * (4*wid)
        unsigned rr[6];
#pragma unroll
        for (int i = 0; i < 6; ++i) {
            int bit = bitbase + 18 * i;
            int w = bit >> 5, sh = bit & 31;
            unsigned long long v = ((unsigned long long)RM1[w + 1] << 32) | RM1[w];
            rr[i] = (unsigned)(v >> sh);
        }
#pragma unroll
        for (int i = 0; i < 5; ++i) {
            unsigned u = rr[i] | rr[i + 1];
            m2row[i] = (u | (u >> 1)) & 0x1FFFFu;
        }
        if (leftEdge) {
#pragma unroll
            for (int i = 0; i < 5; ++i) m2row[i] &= ~1u;
        }
        if (rightEdge) {
#pragma unroll
            for (int i = 0; i < 5; ++i) m2row[i] &= ~(1u << 16);
        }
        col16bits = ((m2row[0] >> 16) & 1u)        | (((m2row[1] >> 16) & 1u) << 1)
                  | (((m2row[2] >> 16) & 1u) << 2) | (((m2row[3] >> 16) & 1u) << 3)
                  | (((m2row[4] >> 16) & 1u) << 4);
    }

    // --- Phase B (wave-private): h2 rows 4w..4w+4, row-aligned groups ---
    {
        const int kh = g >> 1, kw = g & 1;
        const int rowbase = wid * 4;
        f32x4 bias2;
        bias2[0] = b2v.x; bias2[1] = b2v.y; bias2[2] = b2v.z; bias2[3] = b2v.w;

        short* dst = (g & 2) ? &h2hi[wid][0] : &h2lo[wid][0];
        const int choff = (g & 1) * 4;

        // grp 0..4: row=grp, col=c16 (compile-time lr/dx2; all slots valid)
#pragma unroll
        for (int grp = 0; grp < 5; ++grp) {
            short8 bf = *(const short8*)&h1s[((rowbase + grp + kh) * 18 + c16 + kw) * 8];
            f32x4 acc = __builtin_amdgcn_mfma_f32_16x16x32_bf16(a2f, bf, bias2, 0, 0, 0);
            unsigned m2 = (m2row[grp] >> c16) & 1u;
            short4v hv;
#pragma unroll
            for (int r = 0; r < 4; ++r) hv[r] = (short)f2bfu(prelu(acc[r], a2));
            if (m2 == 0) { hv[0] = 0; hv[1] = 0; hv[2] = 0; hv[3] = 0; }
            *(short4v*)&dst[(grp * 17 + c16) * 8 + choff] = hv;
        }
        // grp 5: col 16, row = c16 (valid lanes c16 < 5)
        {
            int lrc = (c16 < 5) ? c16 : 4;
            short8 bf = *(const short8*)&h1s[((rowbase + lrc + kh) * 18 + 16 + kw) * 8];
            f32x4 acc = __builtin_amdgcn_mfma_f32_16x16x32_bf16(a2f, bf, bias2, 0, 0, 0);
            unsigned m2 = (col16bits >> c16) & 1u;   // 0 for c16 >= 5
            short4v hv;
#pragma unroll
            for (int r = 0; r < 4; ++r) hv[r] = (short)f2bfu(prelu(acc[r], a2));
            if (m2 == 0) { hv[0] = 0; hv[1] = 0; hv[2] = 0; hv[3] = 0; }
            if (c16 < 5) *(short4v*)&dst[(lrc * 17 + 16) * 8 + choff] = hv;
        }
    }
    // no barrier: wave consumes only its own h2 region (lgkmcnt-ordered)

    // --- Phase C (wave-private): 4 output rows; 2 chained MFMAs (K=64) + epilogue ---
    {
        const int kwC = g >> 1, ic8 = g & 1;
        const short* h2sel = ic8 ? &h2hi[wid][0] : &h2lo[wid][0];
        f32x4 bias3;
        bias3[0] = b3v.x; bias3[1] = b3v.y; bias3[2] = b3v.z; bias3[3] = b3v.w;
        const float w4r[4] = {w4v.x, w4v.y, w4v.z, w4v.w};

        // row-fragment reuse: local rows 0..4 read once each
        short8 bfp = *(const short8*)&h2sel[(c16 + kwC) * 8];
#pragma unroll
        for (int j = 0; j < 4; ++j) {
            short8 bfn = *(const short8*)&h2sel[((j + 1) * 17 + c16 + kwC) * 8];
            f32x4 acc = __builtin_amdgcn_mfma_f32_16x16x32_bf16(a3f0, bfp, bias3, 0, 0, 0);
            acc = __builtin_amdgcn_mfma_f32_16x16x32_bf16(a3f1, bfn, acc, 0, 0, 0);
            bfp = bfn;

            float partial = 0.f;
#pragma unroll
            for (int r = 0; r < 4; ++r) partial = fmaf(prelu(acc[r], a3), w4r[r], partial);
            partial += __shfl_xor(partial, 16, 64);   // oc live only in g=0,1

            if (g == 0) {
                unsigned combined = m2row[j] | m2row[j + 1];   // compile-time j
                unsigned m3 = (combined >> c16) & 3u;
                float outv = m3 ? (partial + b4) : 0.f;
                int y = ty0 + wid * 4 + j, x = tx0 + c16;
                if (y < x) {
                    outv = 0.f;
                } else if (y == x && m3) {
                    outv = fmaxf(outv, 0.f) + log1pf(expf(-fabsf(outv)));
                }
                out[((size_t)bz * N + y) * N + x] = outv;
            }
        }
    }
}

extern "C" void kernel_launch(void* const* d_in, const int* in_sizes, int n_in,
                              void* d_out, int out_size, void* d_ws, size_t ws_size,
                              hipStream_t stream) {
    const float* x    = (const float*)d_in[0];
    const int*   mask = (const int*)  d_in[1];
    const float* w1   = (const float*)d_in[2];
    const float* b1   = (const float*)d_in[3];
    const float* a1   = (const float*)d_in[4];
    const float* w2   = (const float*)d_in[5];
    const float* b2   = (const float*)d_in[6];
    const float* a2   = (const float*)d_in[7];
    const float* w3   = (const float*)d_in[8];
    const float* b3   = (const float*)d_in[9];
    const float* a3   = (const float*)d_in[10];
    const float* w4   = (const float*)d_in[11];
    const float* b4   = (const float*)d_in[12];
    float* out = (float*)d_out;
    unsigned short* ws = (unsigned short*)d_ws;   // 3 KB used

    prep_weights<<<dim3(1, 1, 1), 256, 0, stream>>>(w2, w3, ws);

    dim3 grid(2080, 1, 2);   // lower-triangle tiles only; zero tiles fused
    precond_mfma<<<grid, 256, 0, stream>>>(x, mask, w1, b1, a1, b2, a2,
                                           b3, a3, w4, b4, ws, out);
}

// Round 22
// 27.974 us; speedup vs baseline: 1.0048x; 1.0048x over previous
//
#include <hip/hip_runtime.h>
#include <hip/hip_bf16.h>
#include <math.h>

#define N 1024
#define TB 16

typedef __attribute__((ext_vector_type(8))) short short8;
typedef __attribute__((ext_vector_type(4))) short short4v;
typedef __attribute__((ext_vector_type(4))) float f32x4;

// PReLU for 0 <= a <= 1 (here a = 0.25): max(v, a*v) — bit-identical to
// max(v,0) + a*min(v,0). 2 VALU ops.
__device__ __forceinline__ float prelu(float v, float a) {
    return fmaxf(v, a * v);
}

// f32 -> bf16 RNE via hardware cvt (pairs into v_cvt_pk_bf16_f32)
__device__ __forceinline__ unsigned short f2bfu(float f) {
    return __bfloat16_as_ushort(__float2bfloat16(f));
}

// ---------- kernel 1: one-block weight prep (runs once per call) ----------
// ws[0..511]    = W2F  : lane l = khkw*16+oc holds W2[oc][k=g*8+j] at [l*8+j]
// ws[512..1023] = W3F0 : lane l = g*16+c16 holds W3 frag k=g*8+j (k<32); c16>=8 zero
// ws[1024..1535]= W3F1 : same for k>=32
__global__ void prep_weights(const float* __restrict__ w2,
                             const float* __restrict__ w3,
                             unsigned short* __restrict__ ws)
{
    const int tid = threadIdx.x;   // 256 threads
    // W2F: element s = o*32 + i*4 + khkw  ->  lane (khkw*16+o), slot i
    for (int s = tid; s < 512; s += 256) {
        int dst = ((s & 3) * 16 + (s >> 5)) * 8 + ((s >> 2) & 7);
        ws[dst] = f2bfu(w2[s]);
    }
    // zero W3F0/F1 fully (covers c16>=8 lanes), then scatter real values
    for (int q = tid; q < 1024; q += 256) ws[512 + q] = 0;
    __syncthreads();
    // W3: element s (oc=s>>6, i=(s>>2)&15, khkw=s&3):
    //   half = (s>>1)&1 ; g = ((s&1)<<1)|((s>>5)&1) ; j = (s>>2)&7
    for (int s = tid; s < 512; s += 256) {
        int half = (s >> 1) & 1;
        int gg = ((s & 1) << 1) | ((s >> 5) & 1);
        int dst = 512 + half * 512 + ((gg * 16 + (s >> 6)) * 8) + ((s >> 2) & 7);
        ws[dst] = f2bfu(w3[s]);
    }
}

// ---------- kernel 2: main (R20 skeleton, weight staging removed) ----------
__global__ __launch_bounds__(256, 8) void precond_mfma(
    const float* __restrict__ xg, const int* __restrict__ maskg,
    const float* __restrict__ w1, const float* __restrict__ b1, const float* __restrict__ a1p,
    const float* __restrict__ b2, const float* __restrict__ a2p,
    const float* __restrict__ b3, const float* __restrict__ a3p,
    const float* __restrict__ w4, const float* __restrict__ b4p,
    const unsigned short* __restrict__ wsW,
    float* __restrict__ out)
{
    const int tid = threadIdx.x;
    const int bz  = blockIdx.z;
    const int t   = blockIdx.x;

    // ---- triangular mapping: t -> (by, bx), bx <= by ----
    int by = (int)((sqrtf(8.0f * (float)t + 1.0f) - 1.0f) * 0.5f);
    while ((by + 1) * (by + 2) / 2 <= t) ++by;
    while (by * (by + 1) / 2 > t) --by;
    const int bx = t - by * (by + 1) / 2;
    const int ty0 = by * TB, tx0 = bx * TB;

    const int lane = tid & 63, wid = tid >> 6;
    const int c16 = lane & 15, g = lane >> 4;

    // ================= EARLY GLOBAL LOADS (issued up front) =================
    // W2 A-fragment: one coalesced 16B/lane load (prepared fragment-major)
    const short8 a2f = *(const short8*)&wsW[lane * 8];

    // parameter vectors, vectorized — consumed from registers only
    const float4 w1lo = *(const float4*)&w1[0];
    const float4 w1hi = *(const float4*)&w1[4];
    const float4 b1lo = *(const float4*)&b1[0];
    const float4 b1hi = *(const float4*)&b1[4];
    const float4 b2v  = *(const float4*)&b2[g * 4];
    const int gsel = (g < 2) ? g : 0;
    float4 b3v = *(const float4*)&b3[gsel * 4];
    float4 w4v = *(const float4*)&w4[gsel * 4];
    const float a1 = a1p[0], a2 = a2p[0], a3 = a3p[0];
    const float b4 = b4p[0];

    const float w1a[8] = {w1lo.x, w1lo.y, w1lo.z, w1lo.w, w1hi.x, w1hi.y, w1hi.z, w1hi.w};
    const float b1a[8] = {b1lo.x, b1lo.y, b1lo.z, b1lo.w, b1hi.x, b1hi.y, b1hi.z, b1hi.w};

    // Phase A positions (324 over 256 threads: 2 slots)
    const int pA0 = tid;
    const int pA1 = tid + 256;
    const bool s1valid = (pA1 < 324);
    const bool s1wave  = ((tid - lane) + 256 < 324);   // waves 0,1
    const int dyA0 = pA0 / 18, dxA0 = pA0 - dyA0 * 18;
    const int dyA1 = pA1 / 18, dxA1 = pA1 - dyA1 * 18;

    int gy0 = ty0 - 1 + dyA0, gx0 = tx0 - 1 + dxA0;
    const bool in0 = (unsigned)gy0 < N && (unsigned)gx0 < N;
    size_t i0 = in0 ? (((size_t)bz * N + gy0) * N + gx0) : 0;
    const int   mr0 = maskg[i0];
    const float xr0 = xg[i0];

    int mr1 = 0; float xr1 = 0.f; bool in1 = false;
    if (s1wave) {
        int gy1 = ty0 - 1 + dyA1, gx1 = tx0 - 1 + dxA1;
        in1 = s1valid && (unsigned)gy1 < N && (unsigned)gx1 < N;
        size_t i1 = in1 ? (((size_t)bz * N + gy1) * N + gx1) : 0;
        mr1 = maskg[i1];
        xr1 = xg[i1];
    }

    // zero b3/w4 fragments for g>=2 lanes (off critical path)
    if (g >= 2) {
        b3v = make_float4(0.f, 0.f, 0.f, 0.f);
        w4v = make_float4(0.f, 0.f, 0.f, 0.f);
    }

    // ---- fused zero-fill (closed form): upper tile = (row=bx, col=by+1) ----
    if (by < 63) {
        int zy = bx * TB + (tid >> 4), zx = (by + 1) * TB + (tid & 15);
        out[((size_t)bz * N + zy) * N + zx] = 0.f;   // fire-and-forget
    }

    __shared__ __align__(16) short h1s[324 * 8];    // [pos 18x18][8ch] bf16
    __shared__ __align__(16) short h2lo[4][85 * 8]; // per-wave: [pos 5x17][ch 0-7]
    __shared__ __align__(16) short h2hi[4][85 * 8]; // per-wave: [pos 5x17][ch 8-15]
    __shared__ __align__(16) unsigned RM1[12];      // 324-bit layer-1 mask bitmap

    const bool leftEdge  = (tx0 == 0);
    const bool rightEdge = (tx0 == N - TB);

    // ---- Phase A: h1 + ballot mask bitmap (consume early loads) ----
    {
        bool mb = in0 && (mr0 > 0);
        float xv = in0 ? xr0 : 0.f;
        unsigned long long bal = __ballot(mb);
        if (lane == 0) *(uint2*)&RM1[2 * wid] = make_uint2((unsigned)bal, (unsigned)(bal >> 32));
        short8 hv;
#pragma unroll
        for (int ch = 0; ch < 8; ++ch) hv[ch] = (short)f2bfu(prelu(fmaf(xv, w1a[ch], b1a[ch]), a1));
        if (!mb) hv = (short8)0;
        *(short8*)&h1s[pA0 * 8] = hv;

        if (s1wave) {
            bool mb1 = in1 && (mr1 > 0);
            float xv1 = in1 ? xr1 : 0.f;
            unsigned long long bal1 = __ballot(mb1);
            if (lane == 0) *(uint2*)&RM1[2 * (wid + 4)] = make_uint2((unsigned)bal1, (unsigned)(bal1 >> 32));
            if (s1valid) {
                short8 hv1;
#pragma unroll
                for (int ch = 0; ch < 8; ++ch) hv1[ch] = (short)f2bfu(prelu(fmaf(xv1, w1a[ch], b1a[ch]), a1));
                if (!mb1) hv1 = (short8)0;
                *(short8*)&h1s[pA1 * 8] = hv1;
            }
        }
    }
    __syncthreads();   // the ONLY barrier

    // W3 A-fragments: issued here so their L2 latency hides under mask-build
    // and Phase B; consumed only in Phase C. Coalesced 16B/lane, L2-hot.
    const short8 a3f0 = *(const short8*)&wsW[512 + lane * 8];
    const short8 a3f1 = *(const short8*)&wsW[1024 + lane * 8];

    // ---- per-wave spread masks in registers: m2row[5] (17 bits) + col16bits ----
    unsigned m2row[5];
    unsigned col16bits;
    {
        const int bitbase = 72 * wid;     // 18 * (4*wid)
        unsigned rr[6];
#pragma unroll
        for (int i = 0; i < 6; ++i) {
            int bit = bitbase + 18 * i;
            int w = bit >> 5, sh = bit & 31;
            unsigned long long v = ((unsigned long long)RM1[w + 1] << 32) | RM1[w];
            rr[i] = (unsigned)(v >> sh);
        }
#pragma unroll
        for (int i = 0; i < 5; ++i) {
            unsigned u = rr[i] | rr[i + 1];
            m2row[i] = (u | (u >> 1)) & 0x1FFFFu;
        }
        if (leftEdge) {
#pragma unroll
            for (int i = 0; i < 5; ++i) m2row[i] &= ~1u;
        }
        if (rightEdge) {
#pragma unroll
            for (int i = 0; i < 5; ++i) m2row[i] &= ~(1u << 16);
        }
        col16bits = ((m2row[0] >> 16) & 1u)        | (((m2row[1] >> 16) & 1u) << 1)
                  | (((m2row[2] >> 16) & 1u) << 2) | (((m2row[3] >> 16) & 1u) << 3)
                  | (((m2row[4] >> 16) & 1u) << 4);
    }

    // --- Phase B (wave-private): h2 rows 4w..4w+4, row-aligned groups ---
    {
        const int kh = g >> 1, kw = g & 1;
        const int rowbase = wid * 4;
        f32x4 bias2;
        bias2[0] = b2v.x; bias2[1] = b2v.y; bias2[2] = b2v.z; bias2[3] = b2v.w;

        short* dst = (g & 2) ? &h2hi[wid][0] : &h2lo[wid][0];
        const int choff = (g & 1) * 4;

        // grp 0..4: row=grp, col=c16 (compile-time lr/dx2; all slots valid)
#pragma unroll
        for (int grp = 0; grp < 5; ++grp) {
            short8 bf = *(const short8*)&h1s[((rowbase + grp + kh) * 18 + c16 + kw) * 8];
            f32x4 acc = __builtin_amdgcn_mfma_f32_16x16x32_bf16(a2f, bf, bias2, 0, 0, 0);
            unsigned m2 = (m2row[grp] >> c16) & 1u;
            short4v hv;
#pragma unroll
            for (int r = 0; r < 4; ++r) hv[r] = (short)f2bfu(prelu(acc[r], a2));
            if (m2 == 0) { hv[0] = 0; hv[1] = 0; hv[2] = 0; hv[3] = 0; }
            *(short4v*)&dst[(grp * 17 + c16) * 8 + choff] = hv;
        }
        // grp 5: col 16, row = c16 (valid lanes c16 < 5)
        {
            int lrc = (c16 < 5) ? c16 : 4;
            short8 bf = *(const short8*)&h1s[((rowbase + lrc + kh) * 18 + 16 + kw) * 8];
            f32x4 acc = __builtin_amdgcn_mfma_f32_16x16x32_bf16(a2f, bf, bias2, 0, 0, 0);
            unsigned m2 = (col16bits >> c16) & 1u;   // 0 for c16 >= 5
            short4v hv;
#pragma unroll
            for (int r = 0; r < 4; ++r) hv[r] = (short)f2bfu(prelu(acc[r], a2));
            if (m2 == 0) { hv[0] = 0; hv[1] = 0; hv[2] = 0; hv[3] = 0; }
            if (c16 < 5) *(short4v*)&dst[(lrc * 17 + 16) * 8 + choff] = hv;
        }
    }
    // no barrier: wave consumes only its own h2 region (lgkmcnt-ordered)

    // --- Phase C (wave-private): 4 output rows; 2 chained MFMAs (K=64) + epilogue ---
    {
        const int kwC = g >> 1, ic8 = g & 1;
        const short* h2sel = ic8 ? &h2hi[wid][0] : &h2lo[wid][0];
        f32x4 bias3;
        bias3[0] = b3v.x; bias3[1] = b3v.y; bias3[2] = b3v.z; bias3[3] = b3v.w;
        const float w4r[4] = {w4v.x, w4v.y, w4v.z, w4v.w};

        // row-fragment reuse: local rows 0..4 read once each
        short8 bfp = *(const short8*)&h2sel[(c16 + kwC) * 8];
#pragma unroll
        for (int j = 0; j < 4; ++j) {
            short8 bfn = *(const short8*)&h2sel[((j + 1) * 17 + c16 + kwC) * 8];
            f32x4 acc = __builtin_amdgcn_mfma_f32_16x16x32_bf16(a3f0, bfp, bias3, 0, 0, 0);
            acc = __builtin_amdgcn_mfma_f32_16x16x32_bf16(a3f1, bfn, acc, 0, 0, 0);
            bfp = bfn;

            float partial = 0.f;
#pragma unroll
            for (int r = 0; r < 4; ++r) partial = fmaf(prelu(acc[r], a3), w4r[r], partial);
            partial += __shfl_xor(partial, 16, 64);   // oc live only in g=0,1

            if (g == 0) {
                unsigned combined = m2row[j] | m2row[j + 1];   // compile-time j
                unsigned m3 = (combined >> c16) & 3u;
                float outv = m3 ? (partial + b4) : 0.f;
                int y = ty0 + wid * 4 + j, x = tx0 + c16;
                if (y < x) {
                    outv = 0.f;
                } else if (y == x && m3) {
                    outv = fmaxf(outv, 0.f) + log1pf(expf(-fabsf(outv)));
                }
                out[((size_t)bz * N + y) * N + x] = outv;
            }
        }
    }
}

extern "C" void kernel_launch(void* const* d_in, const int* in_sizes, int n_in,
                              void* d_out, int out_size, void* d_ws, size_t ws_size,
                              hipStream_t stream) {
    const float* x    = (const float*)d_in[0];
    const int*   mask = (const int*)  d_in[1];
    const float* w1   = (const float*)d_in[2];
    const float* b1   = (const float*)d_in[3];
    const float* a1   = (const float*)d_in[4];
    const float* w2   = (const float*)d_in[5];
    const float* b2   = (const float*)d_in[6];
    const float* a2   = (const float*)d_in[7];
    const float* w3   = (const float*)d_in[8];
    const float* b3   = (const float*)d_in[9];
    const float* a3   = (const float*)d_in[10];
    const float* w4   = (const float*)d_in[11];
    const float* b4   = (const float*)d_in[12];
    float* out = (float*)d_out;
    unsigned short* ws = (unsigned short*)d_ws;   // 3 KB used

    prep_weights<<<dim3(1, 1, 1), 256, 0, stream>>>(w2, w3, ws);

    dim3 grid(2080, 1, 2);   // lower-triangle tiles only; zero tiles fused
    precond_mfma<<<grid, 256, 0, stream>>>(x, mask, w1, b1, a1, b2, a2,
                                           b3, a3, w4, b4, ws, out);
}

// Round 23
// 24.014 us; speedup vs baseline: 1.1706x; 1.1649x over previous
//
#include <hip/hip_runtime.h>
#include <hip/hip_bf16.h>
#include <math.h>

#define N 1024
#define TB 16

typedef __attribute__((ext_vector_type(8))) short short8;
typedef __attribute__((ext_vector_type(4))) short short4v;
typedef __attribute__((ext_vector_type(4))) float f32x4;

// PReLU via max/min: max(v,0) + a*min(v,0)
__device__ __forceinline__ float prelu(float v, float a) {
    return fmaxf(v, 0.f) + a * fminf(v, 0.f);
}

// f32 -> bf16 RNE via hardware cvt (pairs into v_cvt_pk_bf16_f32)
__device__ __forceinline__ short f2bf(float f) {
    return (short)__bfloat16_as_ushort(__float2bfloat16(f));
}

// R23: R20 (best, 24.05us) + s_setprio(1) around the wave-private MFMA phases
// (B and C). Post-barrier waves are desynchronized and independent across
// blocks, matching the regime where setprio measured +4-7% (T5/attn).
__global__ __launch_bounds__(256, 8) void precond_mfma(
    const float* __restrict__ xg, const int* __restrict__ maskg,
    const float* __restrict__ w1, const float* __restrict__ b1, const float* __restrict__ a1p,
    const float* __restrict__ w2, const float* __restrict__ b2, const float* __restrict__ a2p,
    const float* __restrict__ w3, const float* __restrict__ b3, const float* __restrict__ a3p,
    const float* __restrict__ w4, const float* __restrict__ b4p,
    float* __restrict__ out)
{
    const int tid = threadIdx.x;
    const int bz  = blockIdx.z;
    const int t   = blockIdx.x;

    // ---- triangular mapping: t -> (by, bx), bx <= by ----
    int by = (int)((sqrtf(8.0f * (float)t + 1.0f) - 1.0f) * 0.5f);
    while ((by + 1) * (by + 2) / 2 <= t) ++by;
    while (by * (by + 1) / 2 > t) --by;
    const int bx = t - by * (by + 1) / 2;
    const int ty0 = by * TB, tx0 = bx * TB;

    const int lane = tid & 63, wid = tid >> 6;
    const int c16 = lane & 15, g = lane >> 4;

    // ================= EARLY GLOBAL LOADS (all issued up front) =================
    const float w2r0 = w2[tid];
    const float w2r1 = w2[tid + 256];
    const float w3r0 = w3[tid];
    const float w3r1 = w3[tid + 256];

    // parameter vectors, vectorized — consumed from registers only
    const float4 w1lo = *(const float4*)&w1[0];
    const float4 w1hi = *(const float4*)&w1[4];
    const float4 b1lo = *(const float4*)&b1[0];
    const float4 b1hi = *(const float4*)&b1[4];
    const float4 b2v  = *(const float4*)&b2[g * 4];
    const int gsel = (g < 2) ? g : 0;
    float4 b3v = *(const float4*)&b3[gsel * 4];
    float4 w4v = *(const float4*)&w4[gsel * 4];
    const float a1 = a1p[0], a2 = a2p[0], a3 = a3p[0];
    const float b4 = b4p[0];

    const float w1a[8] = {w1lo.x, w1lo.y, w1lo.z, w1lo.w, w1hi.x, w1hi.y, w1hi.z, w1hi.w};
    const float b1a[8] = {b1lo.x, b1lo.y, b1lo.z, b1lo.w, b1hi.x, b1hi.y, b1hi.z, b1hi.w};

    // Phase A positions (324 over 256 threads: 2 slots)
    const int pA0 = tid;
    const int pA1 = tid + 256;
    const bool s1valid = (pA1 < 324);
    const bool s1wave  = ((tid - lane) + 256 < 324);   // waves 0,1
    const int dyA0 = pA0 / 18, dxA0 = pA0 - dyA0 * 18;
    const int dyA1 = pA1 / 18, dxA1 = pA1 - dyA1 * 18;

    int gy0 = ty0 - 1 + dyA0, gx0 = tx0 - 1 + dxA0;
    const bool in0 = (unsigned)gy0 < N && (unsigned)gx0 < N;
    size_t i0 = in0 ? (((size_t)bz * N + gy0) * N + gx0) : 0;
    const int   mr0 = maskg[i0];
    const float xr0 = xg[i0];

    int mr1 = 0; float xr1 = 0.f; bool in1 = false;
    if (s1wave) {
        int gy1 = ty0 - 1 + dyA1, gx1 = tx0 - 1 + dxA1;
        in1 = s1valid && (unsigned)gy1 < N && (unsigned)gx1 < N;
        size_t i1 = in1 ? (((size_t)bz * N + gy1) * N + gx1) : 0;
        mr1 = maskg[i1];
        xr1 = xg[i1];
    }

    // zero b3/w4 fragments for g>=2 lanes (off critical path)
    if (g >= 2) {
        b3v = make_float4(0.f, 0.f, 0.f, 0.f);
        w4v = make_float4(0.f, 0.f, 0.f, 0.f);
    }

    // ---- fused zero-fill (closed form): upper tile = (row=bx, col=by+1) ----
    if (by < 63) {
        int zy = bx * TB + (tid >> 4), zx = (by + 1) * TB + (tid & 15);
        out[((size_t)bz * N + zy) * N + zx] = 0.f;   // fire-and-forget
    }

    // fragment-major weight storage: lane l's A-fragment at [l*8] (16B)
    __shared__ __align__(16) short sW2F[512];       // [lane][8]  : W2 frag
    __shared__ __align__(16) short sW3F0[512];      // [lane][8]  : W3 frag k<32
    __shared__ __align__(16) short sW3F1[512];      // [lane][8]  : W3 frag k>=32
    __shared__ __align__(16) short h1s[324 * 8];    // [pos 18x18][8ch] bf16
    __shared__ __align__(16) short h2lo[4][85 * 8]; // per-wave: [pos 5x17][ch 0-7]
    __shared__ __align__(16) short h2hi[4][85 * 8]; // per-wave: [pos 5x17][ch 8-15]
    __shared__ __align__(16) unsigned RM1[12];      // 324-bit layer-1 mask bitmap

    const bool leftEdge  = (tx0 == 0);
    const bool rightEdge = (tx0 == N - TB);

    // ---- scatter weights into fragment-major LDS (consume early loads) ----
    {
        int s0 = tid, s1 = tid + 256;
        sW2F[((s0 & 3) * 16 + (s0 >> 5)) * 8 + ((s0 >> 2) & 7)] = f2bf(w2r0);
        sW2F[((s1 & 3) * 16 + (s1 >> 5)) * 8 + ((s1 >> 2) & 7)] = f2bf(w2r1);
        short* d0 = (s0 & 2) ? sW3F1 : sW3F0;
        short* d1 = (s1 & 2) ? sW3F1 : sW3F0;
        d0[((((s0 & 1) << 1) | ((s0 >> 5) & 1)) * 16 + (s0 >> 6)) * 8 + ((s0 >> 2) & 7)] = f2bf(w3r0);
        d1[((((s1 & 1) << 1) | ((s1 >> 5) & 1)) * 16 + (s1 >> 6)) * 8 + ((s1 >> 2) & 7)] = f2bf(w3r1);
    }
    // pre-zero the c16>=8 fragment slots of sW3F0/sW3F1
    if (tid < 128) {
        short* z3 = (tid & 64) ? sW3F1 : sW3F0;
        int q = tid & 63;
        int l = ((q >> 4) & 3) * 16 + 8 + ((q >> 1) & 7);
        *(short4v*)&z3[l * 8 + (q & 1) * 4] = (short4v)0;
    }

    // ---- Phase A: h1 + ballot mask bitmap (consume early loads) ----
    {
        bool mb = in0 && (mr0 > 0);
        float xv = in0 ? xr0 : 0.f;
        unsigned long long bal = __ballot(mb);
        if (lane == 0) *(uint2*)&RM1[2 * wid] = make_uint2((unsigned)bal, (unsigned)(bal >> 32));
        short8 hv;
#pragma unroll
        for (int ch = 0; ch < 8; ++ch) hv[ch] = f2bf(prelu(fmaf(xv, w1a[ch], b1a[ch]), a1));
        if (!mb) hv = (short8)0;
        *(short8*)&h1s[pA0 * 8] = hv;

        if (s1wave) {
            bool mb1 = in1 && (mr1 > 0);
            float xv1 = in1 ? xr1 : 0.f;
            unsigned long long bal1 = __ballot(mb1);
            if (lane == 0) *(uint2*)&RM1[2 * (wid + 4)] = make_uint2((unsigned)bal1, (unsigned)(bal1 >> 32));
            if (s1valid) {
                short8 hv1;
#pragma unroll
                for (int ch = 0; ch < 8; ++ch) hv1[ch] = f2bf(prelu(fmaf(xv1, w1a[ch], b1a[ch]), a1));
                if (!mb1) hv1 = (short8)0;
                *(short8*)&h1s[pA1 * 8] = hv1;
            }
        }
    }
    __syncthreads();   // the ONLY barrier

    // ---- per-wave spread masks in registers: m2row[5] (17 bits) + col16bits ----
    unsigned m2row[5];
    unsigned col16bits;
    {
        const int bitbase = 72 * wid;     // 18 * (4*wid)
        unsigned rr[6];
#pragma unroll
        for (int i = 0; i < 6; ++i) {
            int bit = bitbase + 18 * i;
            int w = bit >> 5, sh = bit & 31;
            unsigned long long v = ((unsigned long long)RM1[w + 1] << 32) | RM1[w];
            rr[i] = (unsigned)(v >> sh);
        }
#pragma unroll
        for (int i = 0; i < 5; ++i) {
            unsigned u = rr[i] | rr[i + 1];
            m2row[i] = (u | (u >> 1)) & 0x1FFFFu;
        }
        if (leftEdge) {
#pragma unroll
            for (int i = 0; i < 5; ++i) m2row[i] &= ~1u;
        }
        if (rightEdge) {
#pragma unroll
            for (int i = 0; i < 5; ++i) m2row[i] &= ~(1u << 16);
        }
        col16bits = ((m2row[0] >> 16) & 1u)        | (((m2row[1] >> 16) & 1u) << 1)
                  | (((m2row[2] >> 16) & 1u) << 2) | (((m2row[3] >> 16) & 1u) << 3)
                  | (((m2row[4] >> 16) & 1u) << 4);
    }

    // --- Phase B (wave-private): h2 rows 4w..4w+4, row-aligned groups ---
    __builtin_amdgcn_s_setprio(1);   // MFMA-dense phase: favor on CU scheduler
    {
        short8 a2f = *(const short8*)&sW2F[lane * 8];   // contiguous, conflict-free
        const int kh = g >> 1, kw = g & 1;
        const int rowbase = wid * 4;
        f32x4 bias2;
        bias2[0] = b2v.x; bias2[1] = b2v.y; bias2[2] = b2v.z; bias2[3] = b2v.w;

        short* dst = (g & 2) ? &h2hi[wid][0] : &h2lo[wid][0];
        const int choff = (g & 1) * 4;

        // grp 0..4: row=grp, col=c16 (compile-time lr/dx2; all slots valid)
#pragma unroll
        for (int grp = 0; grp < 5; ++grp) {
            short8 bf = *(const short8*)&h1s[((rowbase + grp + kh) * 18 + c16 + kw) * 8];
            f32x4 acc = __builtin_amdgcn_mfma_f32_16x16x32_bf16(a2f, bf, bias2, 0, 0, 0);
            unsigned m2 = (m2row[grp] >> c16) & 1u;
            short4v hv;
#pragma unroll
            for (int r = 0; r < 4; ++r) hv[r] = f2bf(prelu(acc[r], a2));
            if (m2 == 0) { hv[0] = 0; hv[1] = 0; hv[2] = 0; hv[3] = 0; }
            *(short4v*)&dst[(grp * 17 + c16) * 8 + choff] = hv;
        }
        // grp 5: col 16, row = c16 (valid lanes c16 < 5)
        {
            int lrc = (c16 < 5) ? c16 : 4;
            short8 bf = *(const short8*)&h1s[((rowbase + lrc + kh) * 18 + 16 + kw) * 8];
            f32x4 acc = __builtin_amdgcn_mfma_f32_16x16x32_bf16(a2f, bf, bias2, 0, 0, 0);
            unsigned m2 = (col16bits >> c16) & 1u;   // 0 for c16 >= 5
            short4v hv;
#pragma unroll
            for (int r = 0; r < 4; ++r) hv[r] = f2bf(prelu(acc[r], a2));
            if (m2 == 0) { hv[0] = 0; hv[1] = 0; hv[2] = 0; hv[3] = 0; }
            if (c16 < 5) *(short4v*)&dst[(lrc * 17 + 16) * 8 + choff] = hv;
        }
    }
    // no barrier: wave consumes only its own h2 region (lgkmcnt-ordered)

    // --- Phase C (wave-private): 4 output rows; 2 chained MFMAs (K=64) + epilogue ---
    {
        short8 a3f0 = *(const short8*)&sW3F0[lane * 8];  // contiguous, pre-zeroed c16>=8
        short8 a3f1 = *(const short8*)&sW3F1[lane * 8];
        const int kwC = g >> 1, ic8 = g & 1;
        const short* h2sel = ic8 ? &h2hi[wid][0] : &h2lo[wid][0];
        f32x4 bias3;
        bias3[0] = b3v.x; bias3[1] = b3v.y; bias3[2] = b3v.z; bias3[3] = b3v.w;
        const float w4r[4] = {w4v.x, w4v.y, w4v.z, w4v.w};

        // row-fragment reuse: local rows 0..4 read once each
        short8 bfp = *(const short8*)&h2sel[(c16 + kwC) * 8];
#pragma unroll
        for (int j = 0; j < 4; ++j) {
            short8 bfn = *(const short8*)&h2sel[((j + 1) * 17 + c16 + kwC) * 8];
            f32x4 acc = __builtin_amdgcn_mfma_f32_16x16x32_bf16(a3f0, bfp, bias3, 0, 0, 0);
            acc = __builtin_amdgcn_mfma_f32_16x16x32_bf16(a3f1, bfn, acc, 0, 0, 0);
            bfp = bfn;

            float partial = 0.f;
#pragma unroll
            for (int r = 0; r < 4; ++r) partial = fmaf(prelu(acc[r], a3), w4r[r], partial);
            partial += __shfl_xor(partial, 16, 64);   // oc live only in g=0,1

            if (g == 0) {
                unsigned combined = m2row[j] | m2row[j + 1];   // compile-time j
                unsigned m3 = (combined >> c16) & 3u;
                float outv = m3 ? (partial + b4) : 0.f;
                int y = ty0 + wid * 4 + j, x = tx0 + c16;
                if (y < x) {
                    outv = 0.f;
                } else if (y == x && m3) {
                    outv = fmaxf(outv, 0.f) + log1pf(expf(-fabsf(outv)));
                }
                out[((size_t)bz * N + y) * N + x] = outv;
            }
        }
    }
    __builtin_amdgcn_s_setprio(0);
}

extern "C" void kernel_launch(void* const* d_in, const int* in_sizes, int n_in,
                              void* d_out, int out_size, void* d_ws, size_t ws_size,
                              hipStream_t stream) {
    const float* x    = (const float*)d_in[0];
    const int*   mask = (const int*)  d_in[1];
    const float* w1   = (const float*)d_in[2];
    const float* b1   = (const float*)d_in[3];
    const float* a1   = (const float*)d_in[4];
    const float* w2   = (const float*)d_in[5];
    const float* b2   = (const float*)d_in[6];
    const float* a2   = (const float*)d_in[7];
    const float* w3   = (const float*)d_in[8];
    const float* b3   = (const float*)d_in[9];
    const float* a3   = (const float*)d_in[10];
    const float* w4   = (const float*)d_in[11];
    const float* b4   = (const float*)d_in[12];
    float* out = (float*)d_out;

    dim3 grid(2080, 1, 2);   // lower-triangle tiles only; zero tiles fused
    precond_mfma<<<grid, 256, 0, stream>>>(x, mask, w1, b1, a1, w2, b2, a2,
                                           w3, b3, a3, w4, b4, out);
}